// Round 4
// baseline (242.957 us; speedup 1.0000x reference)
//
#include <hip/hip_runtime.h>
#include <hip/hip_bf16.h>

#define BB 8
#define NN 2048
#define VV 64
#define CHUNK 64            // rows per chunk (one block per chunk)
#define NCHUNK (NN / CHUNK) // 32 chunks per batch
#define WAVES 4

// ---------------------------------------------------------------------------
// Inputs fp32 (reference dtype; round-1 NaN experiment proved fp32 storage).
// Output fp32 (reference output dtype — rounds 2/3 failed ONLY because we
// wrote bf16 into a float* buffer; the "(bf16...)" test label is template
// text, hardcoded in both branches of the generated test).
//
// Math: after causal masking, row i has only two non-structural logits:
//   col 0   : c_i = (h_i.qk_bos) * (h_0.qk_direction)
//   col i-1 : s_i = h_i.qk_previous          (added into col 0 when i==1)
// All other allowed cols (i-1 of them) have logit 0, value h_j*wv. So
//   out_i = [e^{c-m} vbos + e^{s-m} h_{i-1} wv + e^{-m}(S_i - h_{i-1}) wv] / Z
//   Z = e^{c-m} + e^{s-m} + (i-1) e^{-m},  m = max(c,s,0),
//   S_i = sum_{j=1..i} h_j (per channel).
// Row 0: out = vbos (single allowed logit -> weight 1 regardless of value).
// Row 1: 2-way softmax over {c_1+s_1, 0}.
// ---------------------------------------------------------------------------

__global__ __launch_bounds__(256) void fused_attn(
    const float* __restrict__ h,
    const float* __restrict__ wv_bos,
    const float* __restrict__ wv,
    const float* __restrict__ wo_w,
    const float* __restrict__ qk_direction,
    const float* __restrict__ qk_bos,
    const float* __restrict__ qk_previous,
    float* __restrict__ out)
{
  const int tid  = threadIdx.x;
  const int lane = tid & 63;
  const int w    = tid >> 6;          // wave id 0..3
  const int blk  = blockIdx.x;
  const int b    = blk >> 5;          // NCHUNK == 32
  const int c    = blk & 31;
  const int r0   = c * CHUNK;

  __shared__ float s_part[WAVES][VV]; // per-wave prefix partials
  __shared__ float s_c[CHUNK];        // per-row c-dot (h_r . qk_bos)
  __shared__ float s_s[CHUNK];        // per-row s-dot (h_r . qk_previous)
  __shared__ float s_vb[VV];          // vbos = wo_w @ wv_bos
  __shared__ float s_db;              // h[b,0,:].qk_direction

  const float* hb = h + (size_t)b * NN * VV;

  // ---- Phase 1: partial channel prefix over rows 1..r0-1 (wave-split) ----
  {
    float S = 0.f;
    for (int j = 1 + w; j < r0; j += WAVES)
      S += hb[(size_t)j * VV + lane];           // coalesced: lane = channel
    s_part[w][lane] = S;
  }

  // ---- Phase 2a: per-row dot pairs for this chunk's 64 rows (16/wave) ----
  {
    const float qb = qk_bos[lane];
    const float qp = qk_previous[lane];
#pragma unroll 4
    for (int rr = 0; rr < 16; rr++) {
      const int r = r0 + w * 16 + rr;
      const float hv = hb[(size_t)r * VV + lane];
      float cv = hv * qb;
      float sv = hv * qp;
#pragma unroll
      for (int off = 32; off; off >>= 1) {
        cv += __shfl_xor(cv, off, 64);
        sv += __shfl_xor(sv, off, 64);
      }
      if (lane == 0) { s_c[w * 16 + rr] = cv; s_s[w * 16 + rr] = sv; }
    }
  }

  // ---- Phase 2b: vbos (16 output channels per wave; lane = k) ----
  {
    const float wvb = wv_bos[lane];
#pragma unroll 4
    for (int rr = 0; rr < 16; rr++) {
      const int ch = w * 16 + rr;
      float p = wo_w[(size_t)ch * VV + lane] * wvb;
#pragma unroll
      for (int off = 32; off; off >>= 1) p += __shfl_xor(p, off, 64);
      if (lane == 0) s_vb[ch] = p;
    }
  }

  // ---- Phase 2c: db (wave 0) ----
  if (w == 0) {
    float p = hb[lane] * qk_direction[lane];
#pragma unroll
    for (int off = 32; off; off >>= 1) p += __shfl_xor(p, off, 64);
    if (lane == 0) s_db = p;
  }

  __syncthreads();

  // ---- Phase 3: emit (wave 0 only; lane = channel) ----
  if (w == 0) {
    float S = s_part[0][lane] + s_part[1][lane] + s_part[2][lane] + s_part[3][lane];
    const float vb  = s_vb[lane];
    const float dbb = s_db;
    const float wvc = wv[lane];
    float prev = (r0 > 0) ? hb[(size_t)(r0 - 1) * VV + lane] : 0.f;

    for (int t = 0; t < CHUNK; t++) {
      const int ri = r0 + t;
      const float hv = hb[(size_t)ri * VV + lane];
      if (ri > 0) S += hv;                       // S_i = sum_{j=1..i} h_j
      const float ci = s_c[t] * dbb;
      const float si = s_s[t];
      float o;
      if (ri == 0) {
        o = vb;
      } else if (ri == 1) {
        const float l  = ci + si;                // combined logit at col 0
        const float m  = fmaxf(l, 0.f);
        const float e0 = __expf(l - m);
        const float e1 = __expf(-m);
        o = (e0 * vb + e1 * hv * wvc) / (e0 + e1);
      } else {
        const float m  = fmaxf(fmaxf(ci, si), 0.f);
        const float e0 = __expf(ci - m);
        const float es = __expf(si - m);
        const float ew = __expf(-m);
        const float Z  = e0 + es + (float)(ri - 1) * ew;
        o = (e0 * vb + (es - ew) * prev * wvc + ew * S * wvc) / Z;
      }
      out[((size_t)b * NN + ri) * VV + lane] = o;
      prev = hv;
    }
  }
}

extern "C" void kernel_launch(void* const* d_in, const int* in_sizes, int n_in,
                              void* d_out, int out_size, void* d_ws, size_t ws_size,
                              hipStream_t stream)
{
  const float* h       = (const float*)d_in[0];
  // d_in[1] = mask_one, d_in[2] = mask_zero — structural (causal), unused
  const float* wv_bos  = (const float*)d_in[3];
  const float* wv      = (const float*)d_in[4];
  const float* wo_w    = (const float*)d_in[5];
  const float* qk_dir  = (const float*)d_in[6];
  const float* qk_bos  = (const float*)d_in[7];
  const float* qk_prev = (const float*)d_in[8];
  float* outp = (float*)d_out;

  dim3 grid(BB * NCHUNK), block(256);
  hipLaunchKernelGGL(fused_attn, grid, block, 0, stream,
                     h, wv_bos, wv, wo_w, qk_dir, qk_bos, qk_prev, outp);
}

// Round 5
// 106.169 us; speedup vs baseline: 2.2884x; 2.2884x over previous
//
#include <hip/hip_runtime.h>

#define BB 8
#define NN 2048
#define VV 64
#define GR 32                 // rows per group (one wave per group)
#define NG (NN / GR)          // 64 groups per batch

// ---------------------------------------------------------------------------
// Inputs fp32, output fp32 (verified round 4: absmax 7.8e-3).
//
// Closed form: after causal masking, row i has only two non-structural
// logits: col 0 = c_i = (h_i.qk_bos)*(h_0.qk_direction), col i-1 = s_i =
// h_i.qk_previous (added into col 0 when i==1); the other (i-1) allowed
// cols have logit 0 with value h_j*wv. With S_i = sum_{j=1..i} h_j:
//   out_i = [e^{c-m} vbos + (e^{s-m}-e^{-m}) h_{i-1} wv + e^{-m} S_i wv] / Z
//   Z = e^{c-m} + e^{s-m} + (i-1) e^{-m},  m = max(c,s,0)
// Row 0: out = vbos.  Row 1: 2-way softmax over {c_1+s_1, 0}.
//
// R4 lesson: O(N^2) per-block rescans serialize on memory latency (VALUBusy
// 1.65%). This version: hierarchical prefix (K1 group sums, K2 short
// MLP'd base sum + 32-row emit). All loops have compile-time or small trip
// counts; manual 8-way accumulators keep >=8 loads in flight.
// ---------------------------------------------------------------------------

// K1: per-group channel sums (excluding row 0), plus vbos and db.
__global__ __launch_bounds__(64) void k1_sums(
    const float* __restrict__ h,
    const float* __restrict__ wv_bos,
    const float* __restrict__ wo_w,
    const float* __restrict__ qk_direction,
    float* __restrict__ parts,   // [BB][NG][VV]
    float* __restrict__ vbos,    // [VV]
    float* __restrict__ db)      // [BB]
{
  const int lane = threadIdx.x;
  const int blk  = blockIdx.x;        // b*NG + g
  const int b    = blk >> 6;          // NG == 64
  const int g    = blk & 63;

  const float* hp = h + ((size_t)b * NN + (size_t)g * GR) * VV + lane;
  float a0 = 0.f, a1 = 0.f, a2 = 0.f, a3 = 0.f;
#pragma unroll
  for (int t = 0; t < GR; t += 4) {   // 4 independent accumulators -> MLP
    a0 += hp[(t + 0) * VV];
    a1 += hp[(t + 1) * VV];
    a2 += hp[(t + 2) * VV];
    a3 += hp[(t + 3) * VV];
  }
  float s = (a0 + a1) + (a2 + a3);
  if (g == 0) s -= hp[0];             // prefix S excludes row 0 (vbos slot)
  parts[(size_t)blk * VV + lane] = s;

  if (blk == 0) {
    // vbos[ch] = sum_k wo_w[ch,k]*wv_bos[k]; 16KB matrix -> L1 after 1st pass
    const float* wrow = wo_w + (size_t)lane * VV;
    float vb = 0.f;
#pragma unroll 8
    for (int k = 0; k < VV; k++) vb += wrow[k] * wv_bos[k];
    vbos[lane] = vb;

    // db[b] = h[b,0,:].qk_direction
    const float qd = qk_direction[lane];
    for (int bb = 0; bb < BB; bb++) {
      float p = h[(size_t)bb * NN * VV + lane] * qd;
#pragma unroll
      for (int off = 32; off; off >>= 1) p += __shfl_xor(p, off, 64);
      if (lane == 0) db[bb] = p;
    }
  }
}

// K2: one wave per 32-row group. Base prefix from parts (8-way MLP), then
// closed-form emit with in-register shfl dot reductions. No LDS.
__global__ __launch_bounds__(64) void k2_emit(
    const float* __restrict__ h,
    const float* __restrict__ wv,
    const float* __restrict__ qk_bos,
    const float* __restrict__ qk_previous,
    const float* __restrict__ parts,
    const float* __restrict__ vbos,
    const float* __restrict__ db,
    float* __restrict__ out)
{
  const int lane = threadIdx.x;
  const int blk  = blockIdx.x;
  const int b    = blk >> 6;
  const int g    = blk & 63;
  const int r0   = g * GR;

  // base prefix: sum of prior groups' channel sums, 8 loads in flight
  const float* pb = parts + (size_t)b * NG * VV + lane;
  float s0=0.f,s1=0.f,s2=0.f,s3=0.f,s4=0.f,s5=0.f,s6=0.f,s7=0.f;
  int k = 0;
  for (; k + 8 <= g; k += 8) {
    s0 += pb[(k+0)*VV]; s1 += pb[(k+1)*VV]; s2 += pb[(k+2)*VV]; s3 += pb[(k+3)*VV];
    s4 += pb[(k+4)*VV]; s5 += pb[(k+5)*VV]; s6 += pb[(k+6)*VV]; s7 += pb[(k+7)*VV];
  }
  for (; k < g; k++) s0 += pb[k*VV];
  float S = ((s0+s1)+(s2+s3)) + ((s4+s5)+(s6+s7));

  const float vb  = vbos[lane];
  const float dbb = db[b];
  const float wvc = wv[lane];
  const float qb  = qk_bos[lane];
  const float qp  = qk_previous[lane];

  const float* hb = h + (size_t)b * NN * VV;
  float prev = (g > 0) ? hb[(size_t)(r0 - 1) * VV + lane] : 0.f;

#pragma unroll 4
  for (int t = 0; t < GR; t++) {
    const int ri = r0 + t;
    const float hv = hb[(size_t)ri * VV + lane];
    if (ri > 0) S += hv;                     // S_i = sum_{j=1..i} h_j
    // dot pair via butterfly (all lanes end with the full sum)
    float cv = hv * qb, sv = hv * qp;
#pragma unroll
    for (int off = 32; off; off >>= 1) {
      cv += __shfl_xor(cv, off, 64);
      sv += __shfl_xor(sv, off, 64);
    }
    const float ci = cv * dbb;
    const float si = sv;
    float o;
    if (ri == 0) {
      o = vb;
    } else if (ri == 1) {
      const float l  = ci + si;              // combined logit at col 0
      const float m  = fmaxf(l, 0.f);
      const float e0 = __expf(l - m);
      const float e1 = __expf(-m);
      o = (e0 * vb + e1 * hv * wvc) / (e0 + e1);
    } else {
      const float m  = fmaxf(fmaxf(ci, si), 0.f);
      const float e0 = __expf(ci - m);
      const float es = __expf(si - m);
      const float ew = __expf(-m);
      const float Z  = e0 + es + (float)(ri - 1) * ew;
      o = (e0 * vb + (es - ew) * prev * wvc + ew * S * wvc) / Z;
    }
    out[((size_t)b * NN + ri) * VV + lane] = o;
    prev = hv;
  }
}

extern "C" void kernel_launch(void* const* d_in, const int* in_sizes, int n_in,
                              void* d_out, int out_size, void* d_ws, size_t ws_size,
                              hipStream_t stream)
{
  const float* h       = (const float*)d_in[0];
  // d_in[1] = mask_one, d_in[2] = mask_zero — structural (causal), unused
  const float* wv_bos  = (const float*)d_in[3];
  const float* wv      = (const float*)d_in[4];
  const float* wo_w    = (const float*)d_in[5];
  const float* qk_dir  = (const float*)d_in[6];
  const float* qk_bos  = (const float*)d_in[7];
  const float* qk_prev = (const float*)d_in[8];
  float* outp = (float*)d_out;

  float* ws    = (float*)d_ws;
  float* parts = ws;                           // BB*NG*VV floats = 128 KiB
  float* vbos  = parts + BB * NG * VV;         // VV floats
  float* db    = vbos + VV;                    // BB floats

  dim3 block(64);
  hipLaunchKernelGGL(k1_sums, dim3(BB * NG), block, 0, stream,
                     h, wv_bos, wo_w, qk_dir, parts, vbos, db);
  hipLaunchKernelGGL(k2_emit, dim3(BB * NG), block, 0, stream,
                     h, wv, qk_bos, qk_prev, parts, vbos, db, outp);
}